// Round 3
// baseline (237.149 us; speedup 1.0000x reference)
//
#include <hip/hip_runtime.h>

typedef _Float16 f16;
typedef _Float16 f16x8 __attribute__((ext_vector_type(8)));
typedef _Float16 f16x4 __attribute__((ext_vector_type(4)));
typedef float f32x4 __attribute__((ext_vector_type(4)));

#define NR_ 16256
#define NO_ 128
#define NB_ 16

__device__ __forceinline__ f32x4 MF(f16x8 a, f16x8 b, f32x4 c) {
    return __builtin_amdgcn_mfma_f32_16x16x32_f16(a, b, c, 0, 0, 0);
}

// ---------------- prep: fp32 -> f16 weight copies + objects^T + er zero ----------------
__global__ void kprep(const float* __restrict__ rW0, const float* __restrict__ rW1,
                      const float* __restrict__ rW2, const float* __restrict__ objects,
                      f16* W0b, f16* W1b, f16* W2b, f16* OT, float* er)
{
    int i = blockIdx.x * 256 + threadIdx.x, n = gridDim.x * 256;
    for (int j = i; j < 40960; j += n) W0b[j] = (f16)rW0[j];
    for (int j = i; j < 65536; j += n) W1b[j] = (f16)rW1[j];
    for (int j = i; j < 32768; j += n) W2b[j] = (f16)rW2[j];
    for (int j = i; j < 131072; j += n) {
        int b = j >> 13, rem = j & 8191, o = rem >> 6, d = rem & 63;
        OT[((size_t)b << 13) + (d << 7) + o] = (f16)objects[j];  // OT[b][d][o]
    }
    for (int j = i; j < NB_ * 128 * 128; j += n) er[j] = 0.f;
}

// one MLP layer: M=64 rows (4 m-frags), wave covers 32 output cols (2 n-frags)
template<int KSTEPS, int K>
__device__ __forceinline__ void mlp64(const f16* As, int astr, const f16* __restrict__ Wb,
                                      const float* __restrict__ bias, f16* Os, int ostr,
                                      int n0, int l15, int lq)
{
    f32x4 acc[4][2] = {};
#pragma unroll
    for (int ks = 0; ks < KSTEPS; ks++) {
        f16x8 b0 = *(const f16x8*)(Wb + (size_t)(n0 + l15) * K + ks * 32 + (lq << 3));
        f16x8 b1 = *(const f16x8*)(Wb + (size_t)(n0 + 16 + l15) * K + ks * 32 + (lq << 3));
#pragma unroll
        for (int m = 0; m < 4; m++) {
            f16x8 af = *(const f16x8*)(As + (m * 16 + l15) * astr + ks * 32 + (lq << 3));
            acc[m][0] = MF(af, b0, acc[m][0]);
            acc[m][1] = MF(af, b1, acc[m][1]);
        }
    }
    float bv0 = bias[n0 + l15], bv1 = bias[n0 + 16 + l15];
#pragma unroll
    for (int m = 0; m < 4; m++) {
        f16* d = Os + (m * 16 + (lq << 2)) * ostr;
#pragma unroll
        for (int q = 0; q < 4; q++) {
            d[q * ostr + n0 + l15]      = (f16)fmaxf(acc[m][0][q] + bv0, 0.f);
            d[q * ostr + n0 + 16 + l15] = (f16)fmaxf(acc[m][1][q] + bv1, 0.f);
        }
    }
}

// ---------------- fused relational kernel: gather + 3-layer MLP + scatter ----------------
__global__ __launch_bounds__(512)
void krel2(const float* __restrict__ SR, const float* __restrict__ RRg,
           const float* __restrict__ RI,
           const f16* __restrict__ W0b, const f16* __restrict__ W1b,
           const f16* __restrict__ W2b,
           const float* __restrict__ rb0, const float* __restrict__ rb1,
           const float* __restrict__ rb2,
           const f16* __restrict__ OT, float* __restrict__ er)
{
    __shared__ __align__(16) char smem[125952];
    f16* OTs = (f16*)(smem);            // [64][136]   0..17408   persistent (per block)
    f16* SRt = (f16*)(smem + 17408);    // [64][136]   ..34816    per-tile (phase A)
    f16* RRt = (f16*)(smem + 34816);    // [64][136]   ..52224    per-tile (phase A)
    f16* xs  = (f16*)(smem + 52224);    // [64][168]   ..73728    staging+gather -> L1
    f16* RRs = (f16*)(smem + 73728);    // [128][72]   ..92160    per-tile, live until scatter
    f16* h2s = (f16*)(smem + 92160);    // [64][264]   ..125952
    f16* h1s = (f16*)(smem + 17408);    // [64][264]  aliases SRt+RRt (dead after gather)
    f16* EtS = (f16*)(smem + 52224);    // [128][72]  aliases xs (dead after L1)

    const int b = blockIdx.y;
    const int grp = blockIdx.x;          // 16 groups
    const int tid = threadIdx.x;
    const int lane = tid & 63;
    const int wave = tid >> 6;
    const int l15 = lane & 15;
    const int lq = lane >> 4;

    // stage O^T once per block: OTs[d][o], d=0..63, o=0..127
    for (int c = tid; c < 1024; c += 512) {
        int d = c >> 4, ko = (c & 15) << 3;
        *(f16x8*)(OTs + d * 136 + ko) = *(const f16x8*)(OT + ((size_t)b * 64 + d) * 128 + ko);
    }

    f32x4 asc[8] = {};   // scatter accum: o-frag = wave, e-frags 0..7

    for (int t = grp; t < 254; t += 16) {
        const int r0 = t * 64;

        // ---- stage SR^T, RR^T (transposed, [r][o]) and RR straight ([o][r]) ----
        for (int c = tid; c < 1024; c += 512) {
            int o = c >> 3, rh = (c & 7) << 3;
            const float* ps = SR + ((size_t)b * NO_ + o) * NR_ + r0 + rh;
            const float* pr = RRg + ((size_t)b * NO_ + o) * NR_ + r0 + rh;
            float4 s0 = *(const float4*)ps, s1 = *(const float4*)(ps + 4);
            float4 q0 = *(const float4*)pr, q1 = *(const float4*)(pr + 4);
            f16* ds = SRt + rh * 136 + o;
            ds[0*136] = (f16)s0.x; ds[1*136] = (f16)s0.y; ds[2*136] = (f16)s0.z; ds[3*136] = (f16)s0.w;
            ds[4*136] = (f16)s1.x; ds[5*136] = (f16)s1.y; ds[6*136] = (f16)s1.z; ds[7*136] = (f16)s1.w;
            f16* dr = RRt + rh * 136 + o;
            dr[0*136] = (f16)q0.x; dr[1*136] = (f16)q0.y; dr[2*136] = (f16)q0.z; dr[3*136] = (f16)q0.w;
            dr[4*136] = (f16)q1.x; dr[5*136] = (f16)q1.y; dr[6*136] = (f16)q1.z; dr[7*136] = (f16)q1.w;
            f16x8 rrv;
            rrv[0] = (f16)q0.x; rrv[1] = (f16)q0.y; rrv[2] = (f16)q0.z; rrv[3] = (f16)q0.w;
            rrv[4] = (f16)q1.x; rrv[5] = (f16)q1.y; rrv[6] = (f16)q1.z; rrv[7] = (f16)q1.w;
            *(f16x8*)(RRs + o * 72 + rh) = rrv;
        }
        // ---- stage relation_info into x[:,128:160] ----
        {
            int rr = tid >> 3, cc = (tid & 7) << 2;
            float4 v = *(const float4*)(RI + ((size_t)b * NR_ + r0 + rr) * 32 + cc);
            f16* d = xs + rr * 168 + 128 + cc;
            d[0] = (f16)v.x; d[1] = (f16)v.y; d[2] = (f16)v.z; d[3] = (f16)v.w;
        }
        __syncthreads();

        // ---- gather: waves 0-3 senders (x cols 0-63), waves 4-7 receivers (64-127) ----
        {
            const f16* At = (wave < 4) ? SRt : RRt;
            const int nf = wave & 3;
            const int xcol = (wave < 4) ? 0 : 64;
            f32x4 acc[4] = {};
#pragma unroll
            for (int ks = 0; ks < 4; ks++) {
                f16x8 bf = *(const f16x8*)(OTs + (nf * 16 + l15) * 136 + ks * 32 + (lq << 3));
#pragma unroll
                for (int m = 0; m < 4; m++) {
                    f16x8 af = *(const f16x8*)(At + (m * 16 + l15) * 136 + ks * 32 + (lq << 3));
                    acc[m] = MF(af, bf, acc[m]);
                }
            }
#pragma unroll
            for (int m = 0; m < 4; m++) {
                f16* d = xs + (m * 16 + (lq << 2)) * 168 + xcol + nf * 16 + l15;
                d[0*168] = (f16)acc[m][0]; d[1*168] = (f16)acc[m][1];
                d[2*168] = (f16)acc[m][2]; d[3*168] = (f16)acc[m][3];
            }
        }
        __syncthreads();

        mlp64<5, 160>(xs, 168, W0b, rb0, h1s, 264, wave * 32, l15, lq);
        __syncthreads();
        mlp64<8, 256>(h1s, 264, W1b, rb1, h2s, 264, wave * 32, l15, lq);
        __syncthreads();

        // ---- layer3 -> effects^T [e][r] in LDS (EtS, k-major r) ----
        {
            const int n0 = wave * 16;
            const int e = n0 + l15;
            f32x4 acc[4] = {};
#pragma unroll
            for (int ks = 0; ks < 8; ks++) {
                f16x8 bf = *(const f16x8*)(W2b + (size_t)e * 256 + ks * 32 + (lq << 3));
#pragma unroll
                for (int m = 0; m < 4; m++) {
                    f16x8 af = *(const f16x8*)(h2s + (m * 16 + l15) * 264 + ks * 32 + (lq << 3));
                    acc[m] = MF(af, bf, acc[m]);
                }
            }
            float bv = rb2[e];
#pragma unroll
            for (int m = 0; m < 4; m++) {
                f16x4 pk;
#pragma unroll
                for (int q = 0; q < 4; q++) pk[q] = (f16)fmaxf(acc[m][q] + bv, 0.f);
                *(f16x4*)(EtS + e * 72 + m * 16 + (lq << 2)) = pk;   // rows r = m*16+lq*4+q
            }
        }
        __syncthreads();

        // ---- scatter partial: asc[nf] += RRs(o rows) x EtS(e rows), K = 64 r ----
        {
            const int ow = wave * 16;
#pragma unroll
            for (int ks = 0; ks < 2; ks++) {
                f16x8 af = *(const f16x8*)(RRs + (ow + l15) * 72 + ks * 32 + (lq << 3));
#pragma unroll
                for (int nf = 0; nf < 8; nf++) {
                    f16x8 bf = *(const f16x8*)(EtS + (nf * 16 + l15) * 72 + ks * 32 + (lq << 3));
                    asc[nf] = MF(af, bf, asc[nf]);
                }
            }
        }
        __syncthreads();   // protect RRs/EtS/xs/SRt/RRt before next tile's staging
    }

    // ---- commit scatter partials ----
    float* dst = er + ((size_t)b << 14);
#pragma unroll
    for (int nf = 0; nf < 8; nf++) {
        int e = nf * 16 + l15;
#pragma unroll
        for (int q = 0; q < 4; q++) {
            int o = wave * 16 + (lq << 2) + q;
            atomicAdd(dst + (size_t)o * 128 + e, asc[nf][q]);
        }
    }
}

// ---------------- object MLP, all-f32 VALU, f32 output ----------------
__global__ __launch_bounds__(256)
void kobj32(const float* __restrict__ objects, const float* __restrict__ er,
            const float* __restrict__ oW0, const float* __restrict__ oW1,
            const float* __restrict__ oW2,
            const float* __restrict__ ob0, const float* __restrict__ ob1,
            const float* __restrict__ ob2, float* __restrict__ out)
{
    __shared__ float ys[8][192];
    __shared__ float h1[8][256];
    __shared__ float h2[8][128];
    const int r0 = blockIdx.x * 8;        // 256 blocks x 8 rows = 2048 rows (b*128+o)
    const int tid = threadIdx.x;

    for (int c = tid; c < 8 * 192; c += 256) {
        int rr = c / 192, k = c % 192;
        ys[rr][k] = (k < 64) ? objects[(size_t)(r0 + rr) * 64 + k]
                             : er[(size_t)(r0 + rr) * 128 + (k - 64)];
    }
    __syncthreads();
    for (int c = tid; c < 8 * 256; c += 256) {   // layer1: K=192, N=256
        int rr = c >> 8, n = c & 255;
        const float* w = oW0 + (size_t)n * 192;
        float s = ob0[n];
        for (int k = 0; k < 192; k++) s += ys[rr][k] * w[k];
        h1[rr][n] = fmaxf(s, 0.f);
    }
    __syncthreads();
    for (int c = tid; c < 8 * 128; c += 256) {   // layer2: K=256, N=128
        int rr = c >> 7, n = c & 127;
        const float* w = oW1 + (size_t)n * 256;
        float s = ob1[n];
        for (int k = 0; k < 256; k++) s += h1[rr][k] * w[k];
        h2[rr][n] = fmaxf(s, 0.f);
    }
    __syncthreads();
    for (int c = tid; c < 24; c += 256) {        // layer3: N=3
        int rr = c / 3, j = c % 3;
        const float* w = oW2 + j * 128;
        float s = ob2[j];
        for (int k = 0; k < 128; k++) s += h2[rr][k] * w[k];
        out[(size_t)(r0 + rr) * 3 + j] = s;
    }
}

extern "C" void kernel_launch(void* const* d_in, const int* in_sizes, int n_in,
                              void* d_out, int out_size, void* d_ws, size_t ws_size,
                              hipStream_t stream)
{
    (void)in_sizes; (void)n_in; (void)out_size; (void)ws_size;
    const float* objects = (const float*)d_in[0];
    const float* SR  = (const float*)d_in[1];
    const float* RRg = (const float*)d_in[2];
    const float* RI  = (const float*)d_in[3];
    const float* rW0 = (const float*)d_in[4];
    const float* rb0 = (const float*)d_in[5];
    const float* rW1 = (const float*)d_in[6];
    const float* rb1 = (const float*)d_in[7];
    const float* rW2 = (const float*)d_in[8];
    const float* rb2 = (const float*)d_in[9];
    const float* oW0 = (const float*)d_in[10];
    const float* ob0 = (const float*)d_in[11];
    const float* oW1 = (const float*)d_in[12];
    const float* ob1 = (const float*)d_in[13];
    const float* oW2 = (const float*)d_in[14];
    const float* ob2 = (const float*)d_in[15];

    char* ws = (char*)d_ws;
    f16* W0b = (f16*)(ws + 0);             // 81920 B
    f16* W1b = (f16*)(ws + 81920);         // 131072 B
    f16* W2b = (f16*)(ws + 212992);        // 65536 B
    f16* OT  = (f16*)(ws + 278528);        // 262144 B
    float* er = (float*)(ws + 540672);     // 1048576 B  (total ~1.6 MB)

    hipLaunchKernelGGL(kprep, dim3(512), dim3(256), 0, stream,
                       rW0, rW1, rW2, objects, W0b, W1b, W2b, OT, er);
    hipLaunchKernelGGL(krel2, dim3(16, 16), dim3(512), 0, stream,
                       SR, RRg, RI, W0b, W1b, W2b, rb0, rb1, rb2, OT, er);
    hipLaunchKernelGGL(kobj32, dim3(256), dim3(256), 0, stream,
                       objects, er, oW0, oW1, oW2, ob0, ob1, ob2, (float*)d_out);
}